// Round 10
// baseline (326.819 us; speedup 1.0000x reference)
//
#include <hip/hip_runtime.h>

// GQA fused pipeline, bf16 MFMA, gfx950.
// cvt(fp32->bf16) -> fused QKV GEMM (R7: 2-K-tile/8-phase counted-vmcnt,
// asm ds_reads, T2 swizzle + T5 setprio) -> flash attention (R10: one q-tile
// per block, 4 heads x 2 KV-parity waves, additive m=0-softmax merge;
// halves the heaviest block's critical path and removes light-group idling)
// -> Wo GEMM (same schedule, 256x128 tile).

#define B_   2
#define S_   2048
#define DIN  2048
#define NH   32
#define NKV  8
#define HD   64
#define DOUT 2048
#define NQKV 3072

#define QSCALE 0.18033688f  // 0.125 * log2(e), folded into Q

typedef short bf16x8 __attribute__((ext_vector_type(8)));
typedef short bf16x4 __attribute__((ext_vector_type(4)));
typedef float f32x4  __attribute__((ext_vector_type(4)));

__device__ __forceinline__ unsigned short f2bf(float f) {
  unsigned int u = __float_as_uint(f);
  u += 0x7fff + ((u >> 16) & 1);  // RNE
  return (unsigned short)(u >> 16);
}

__device__ __forceinline__ f32x4 mfma16(bf16x4 a, bf16x4 b, f32x4 c) {
#if __has_builtin(__builtin_amdgcn_mfma_f32_16x16x16bf16_1k)
  return __builtin_amdgcn_mfma_f32_16x16x16bf16_1k(a, b, c, 0, 0, 0);
#else
  asm volatile("v_mfma_f32_16x16x16_bf16 %0, %1, %2, %0" : "+v"(c) : "v"(a), "v"(b));
  return c;
#endif
}

__device__ __forceinline__ void gld_lds16(const void* gptr, void* lptr) {
  __builtin_amdgcn_global_load_lds(
      (const __attribute__((address_space(1))) unsigned int*)gptr,
      (__attribute__((address_space(3))) unsigned int*)lptr,
      16, 0, 0);
}

// Inline-asm LDS reads (GEMM only): invisible to the backend's aliasing
// analysis; ordering is the ledger's job (counted lgkm + sched_barrier).
__device__ __forceinline__ bf16x8 ds_read128(const unsigned short* p) {
  bf16x8 r;
  asm volatile("ds_read_b128 %0, %1"
               : "=v"(r)
               : "v"((const __attribute__((address_space(3))) unsigned short*)p));
  return r;
}

#define BAR() __builtin_amdgcn_s_barrier()
#define SB()  __builtin_amdgcn_sched_barrier(0)
#define VMCNT(n) asm volatile("s_waitcnt vmcnt(" #n ")")
#define LGKM(n)                                   \
  do {                                            \
    asm volatile("s_waitcnt lgkmcnt(" #n ")");    \
    __builtin_amdgcn_sched_barrier(0);            \
  } while (0)
#define LGKM0() LGKM(0)

// single conversion kernel for all 5 tensors (boundaries multiples of 256).
__global__ __launch_bounds__(256) void cvt_all(
    const float* __restrict__ x,  const float* __restrict__ Wq,
    const float* __restrict__ Wk, const float* __restrict__ Wv,
    const float* __restrict__ Wo,
    unsigned short* __restrict__ xbf, unsigned short* __restrict__ wqkv,
    unsigned short* __restrict__ wobf) {
  int i = blockIdx.x * blockDim.x + threadIdx.x;
  const float* src; unsigned short* dst; int off;
  if (i < 2097152)      { src = x;  dst = xbf;                  off = i; }
  else if (i < 3145728) { src = Wq; dst = wqkv;                 off = i - 2097152; }
  else if (i < 3407872) { src = Wk; dst = wqkv + 2048 * 2048;   off = i - 3145728; }
  else if (i < 3670016) { src = Wv; dst = wqkv + 2560 * 2048;   off = i - 3407872; }
  else                  { src = Wo; dst = wobf;                 off = i - 3670016; }
  float4 f = ((const float4*)src)[off];
  ushort4 o;
  o.x = f2bf(f.x); o.y = f2bf(f.y); o.z = f2bf(f.z); o.w = f2bf(f.w);
  ((ushort4*)dst)[off] = o;
}

// C = A @ B^T, 256x(BN) tile, BK=64, 8 waves (2M x 4N), 512 threads.
// (R7 schedule, unchanged — best verified GEMM of this session.)
#define MMA_PHASE(MH, NHH, AF, BF)                                              \
  do {                                                                          \
    __builtin_amdgcn_s_setprio(1);                                              \
    _Pragma("unroll")                                                           \
    for (int kk = 0; kk < 2; ++kk)                                              \
      _Pragma("unroll")                                                         \
      for (int mr = 0; mr < 4; ++mr)                                            \
        _Pragma("unroll")                                                       \
        for (int nr = 0; nr < NR; ++nr)                                         \
          acc[(MH) * 4 + mr][(NHH) * NR + nr] =                                 \
              __builtin_amdgcn_mfma_f32_16x16x32_bf16(                          \
                  AF[mr][kk], BF[nr][kk], acc[(MH) * 4 + mr][(NHH) * NR + nr],  \
                  0, 0, 0);                                                     \
    __builtin_amdgcn_s_setprio(0);                                              \
  } while (0)

#define WAITW()                                   \
  do {                                            \
    if constexpr (BN == 256) VMCNT(4);            \
    else                     VMCNT(3);            \
  } while (0)

template <int MODE, int BN, int NTN>
__global__ __launch_bounds__(512, 2) void gemm8p(
    const unsigned short* __restrict__ A,
    const unsigned short* __restrict__ Bm,
    int K,
    unsigned short* __restrict__ qbf,
    unsigned short* __restrict__ kbf,
    unsigned short* __restrict__ vtbf,
    float* __restrict__ kout,
    float* __restrict__ vout,
    float* __restrict__ cout) {
  constexpr int NR = BN / 128;        // B fragments per quadrant (2 or 1)
  constexpr int BHROW = BN / 2;       // rows per B half-tile
  __shared__ unsigned short As[2][256 * 64];
  __shared__ unsigned short Bs[2][BN * 64];

  const int tid  = threadIdx.x;
  const int lane = tid & 63;
  const int wave = tid >> 6;  // 0..7
  const int wm   = wave >> 2; // 0..1
  const int wn   = wave & 3;  // 0..3
  const int quad = lane >> 4;
  const int r16  = lane & 15;

  const int NT = K / 64;

  // XCD-aware chunked swizzle on linear block id (gridDim.x % 8 == 0).
  const int nwg = gridDim.x;
  const int id  = blockIdx.x;
  const int sid = (id & 7) * (nwg >> 3) + (id >> 3);
  const int by  = sid / NTN;
  const int bx  = sid % NTN;
  const int aRowBase = by * 256;
  const int bColBase = bx * BN;

  f32x4 zero = {0.f, 0.f, 0.f, 0.f};
  f32x4 acc[8][2 * NR];
#pragma unroll
  for (int i = 0; i < 8; ++i)
#pragma unroll
    for (int j = 0; j < 2 * NR; ++j) acc[i][j] = zero;

  auto stageA = [&](int dbuf, int h, int t) {
    const int tt = t < NT ? t : NT - 1;
    const int k0 = tt * 64;
#pragma unroll
    for (int i = 0; i < 2; ++i) {
      const int chunk = (i * 8 + wave) * 64 + lane;  // 0..1023
      const int row = chunk >> 3;                    // 0..127
      const int slot = chunk & 7;
      const int gc = (slot ^ (row & 7)) * 8;
      gld_lds16(A + (size_t)(aRowBase + h * 128 + row) * K + k0 + gc,
                &As[dbuf][h * 8192 + (i * 8 + wave) * 512]);
    }
  };
  auto stageB = [&](int dbuf, int h, int t) {
    const int tt = t < NT ? t : NT - 1;
    const int k0 = tt * 64;
    if constexpr (BN == 256) {
#pragma unroll
      for (int i = 0; i < 2; ++i) {
        const int chunk = (i * 8 + wave) * 64 + lane;
        const int row = chunk >> 3;
        const int slot = chunk & 7;
        const int gc = (slot ^ (row & 7)) * 8;
        gld_lds16(Bm + (size_t)(bColBase + h * 128 + row) * K + k0 + gc,
                  &Bs[dbuf][h * 8192 + (i * 8 + wave) * 512]);
      }
    } else {
      const int chunk = wave * 64 + lane;  // 0..511
      const int row = chunk >> 3;          // 0..63
      const int slot = chunk & 7;
      const int gc = (slot ^ (row & 7)) * 8;
      gld_lds16(Bm + (size_t)(bColBase + h * 64 + row) * K + k0 + gc,
                &Bs[dbuf][h * 4096 + wave * 512]);
    }
  };

  bf16x8 afA[4][2];     // A-half0 fragments
  bf16x8 afB[4][2];     // A-half1 fragments
  bf16x8 b0[NR][2];     // B-half0 fragments
  bf16x8 b1[NR][2];     // B-half1 fragments

  auto readA = [&](int sbuf, int mh, bf16x8 (&dst)[4][2]) {
#pragma unroll
    for (int mr = 0; mr < 4; ++mr)
#pragma unroll
      for (int kk = 0; kk < 2; ++kk) {
        const int row = mh * 128 + wm * 64 + mr * 16 + r16;
        const int slot = (kk * 4 + quad) ^ (r16 & 7);
        dst[mr][kk] = ds_read128(&As[sbuf][row * 64 + slot * 8]);
      }
  };
  auto readB = [&](int sbuf, int nh, bf16x8 (&dst)[NR][2]) {
#pragma unroll
    for (int nr = 0; nr < NR; ++nr)
#pragma unroll
      for (int kk = 0; kk < 2; ++kk) {
        const int row = nh * BHROW + wn * (BN / 8) + nr * 16 + r16;
        const int slot = (kk * 4 + quad) ^ (r16 & 7);
        dst[nr][kk] = ds_read128(&Bs[sbuf][row * 64 + slot * 8]);
      }
  };

  // --- prologue: mirrors steady state at Ph1 entry.
  stageA(0, 0, 0);   // A0(0)
  stageB(0, 0, 0);   // B0(0)
  stageB(0, 1, 0);   // B1(0)
  stageA(0, 1, 0);   // A1(0)
  stageA(1, 0, 1);   // A0(1)
  stageB(1, 0, 1);   // B0(1)
  WAITW();           // lands tile0; leaves {A0(1),B0(1)}
  BAR();             // PUBLISH tile0
  stageB(1, 1, 1);   // B1(1)
  readA(0, 0, afA);
  readB(0, 0, b0);
  SB();

  const int NIT = NT / 2;
  for (int i = 0; i < NIT; ++i) {
    const int e2 = 2 * i + 2, o2 = 2 * i + 3;

    // Ph1 (e,q00): consume afA,b0; hoist B1(e)->b1.
    stageA(1, 1, 2 * i + 1);              // S1
    BAR();
    LGKM0();
    readB(0, 1, b1); SB();
    MMA_PHASE(0, 0, afA, b0);
    BAR();

    // Ph2 (e,q01): consume afA,b1; hoist A1(e)->afB.
    stageA(0, 0, e2);                     // S2
    BAR();
    LGKM0();
    readA(0, 1, afB); SB();
    MMA_PHASE(0, 1, afA, b1);
    BAR();

    // Ph3 (e,q10): consume afB,b0; counted wait W1 lands tile o.
    stageB(0, 0, e2);                     // S3
    BAR();
    LGKM0();
    MMA_PHASE(1, 0, afB, b0);
    WAITW();
    BAR();                                // PUBLISH tile o

    // Ph4 (e,q11): register-only MFMA; read A0(o),B0(o) overlapping MFMA.
    stageB(0, 1, e2);                     // S4
    BAR();
    readA(1, 0, afA);
    readB(1, 0, b0); SB();
    MMA_PHASE(1, 1, afB, b1);
    BAR();

    // Ph5 (o,q00): consume afA,b0; hoist B1(o)->b1.
    stageA(0, 1, e2);                     // S5
    BAR();
    LGKM0();
    readB(1, 1, b1); SB();
    MMA_PHASE(0, 0, afA, b0);
    BAR();

    // Ph6 (o,q01): consume afA,b1; hoist A1(o)->afB.
    stageA(1, 0, o2);                     // S6
    BAR();
    LGKM0();
    readA(1, 1, afB); SB();
    MMA_PHASE(0, 1, afA, b1);
    BAR();

    // Ph7 (o,q10): consume afB,b0; counted wait W2 lands tile e+2.
    stageB(1, 0, o2);                     // S7
    BAR();
    LGKM0();
    MMA_PHASE(1, 0, afB, b0);
    WAITW();
    BAR();                                // PUBLISH tile e+2

    // Ph8 (o,q11): register-only MFMA; read A0(e'),B0(e') overlapping MFMA.
    stageB(1, 1, o2);                     // S8
    BAR();
    readA(0, 0, afA);
    readB(0, 0, b0); SB();
    MMA_PHASE(1, 1, afB, b1);
    BAR();
  }
  asm volatile("s_waitcnt vmcnt(0) lgkmcnt(0)");  // drain before epilogue

  // --- epilogue: C write.
#pragma unroll
  for (int mi = 0; mi < 8; ++mi) {
    const int mh = mi >> 2, mr = mi & 3;
#pragma unroll
    for (int ni = 0; ni < 2 * NR; ++ni) {
      const int nh = ni / NR, nr = ni % NR;
      const int rowb = aRowBase + mh * 128 + wm * 64 + mr * 16 + quad * 4;
      const int col  = bColBase +
                       (BN == 256 ? nh * 128 + wn * 32 + nr * 16
                                  : nh * 64 + wn * 16) + r16;
#pragma unroll
      for (int reg = 0; reg < 4; ++reg) {
        const float v = acc[mi][ni][reg];
        const int m = rowb + reg;
        if (MODE == 1) {
          cout[(size_t)m * DOUT + col] = v;
        } else {
          if (col < 2048) {
            qbf[(size_t)m * DOUT + col] = f2bf(v * QSCALE);
          } else if (col < 2560) {
            const int gg = (col - 2048) >> 6, d = col & 63;
            const int b = m >> 11, s = m & 2047;
            const size_t idx = ((size_t)(b * NKV + gg) * S_ + s) * HD + d;
            kbf[idx]  = f2bf(v);
            kout[idx] = v;
          } else {
            const int gg = (col - 2560) >> 6, d = col & 63;
            const int b = m >> 11, s = m & 2047;
            vtbf[((size_t)(b * NKV + gg) * HD + d) * S_ + s]  = f2bf(v);
            vout[((size_t)(b * NKV + gg) * S_ + s) * HD + d] = v;
          }
        }
      }
    }
  }
}

// Flash attention, causal, m=0 softmax, in-register P (S^T operand-swap).
// R10 partition: block = ONE q-tile (32 rows) x one KV group. 8 waves =
// 4 heads x 2 KV-parity waves; wave (h,p) processes KV tiles 2s+p. Both
// parity waves are always busy (no light-group idling) and the heaviest
// block's critical path halves (32 tiles -> 16 rounds). m=0 softmax (no
// running max) => partials merge ADDITIVELY: o = o0+o1, l = l0+l1, via an
// LDS exchange after the loop. One __syncthreads per 2 tiles. Plain LDS
// reads + __syncthreads (R1-proven sync; no hand-vmcnt hazards).
// LDS 64 KiB -> 2 blocks/CU; launch_bounds(512,2) -> VGPR cap 256, no spill.
__global__ __launch_bounds__(512, 2) void attn_kernel(
    const unsigned short* __restrict__ Q,   // [B*S][DOUT] bf16 (scaled)
    const unsigned short* __restrict__ Kb,  // [B*NKV][S][HD] bf16
    const unsigned short* __restrict__ VT,  // [B*NKV][HD][S] bf16
    unsigned short* __restrict__ ctx) {     // [B*S][DOUT] bf16
  // 64 KiB: K slots [dbuf][parity] at smem + (d*2+p)*4096,
  //         V slots at smem + 16384 + (d*2+p)*4096. Reused as float
  //         scratch (4 heads x 64 lanes x 41 floats = 42 KB) for the merge.
  __shared__ unsigned short smem[32768];

  const int tid  = threadIdx.x;
  const int lane = tid & 63;
  const int wave = tid >> 6;   // 0..7
  const int hw   = wave >> 1;  // head within group, 0..3
  const int p    = wave & 1;   // KV parity
  const int quad = lane >> 4;
  const int r16  = lane & 15;
  const int j    = 63 - blockIdx.x;  // q-tile index, heavy-first
  const int g    = blockIdx.y;
  const int b    = blockIdx.z;
  const int h    = g * 4 + hw;
  const int q0   = j * 32;
  const int ntiles  = j / 2 + 1;        // 64-key tiles needed (causal)
  const int nrounds = (ntiles + 1) / 2;

  const unsigned short* Kh  = Kb + (size_t)(b * NKV + g) * S_ * HD;
  const unsigned short* VTh = VT + (size_t)(b * NKV + g) * HD * S_;

  const int srow   = lane >> 3;
  const int schunk = (lane & 7) ^ srow;

  // Q fragments (B-operand of S^T MFMA); all 8 waves: same 32 rows, own head.
  bf16x8 aq[2][2];
#pragma unroll
  for (int mt = 0; mt < 2; ++mt)
#pragma unroll
    for (int kk = 0; kk < 2; ++kk)
      aq[mt][kk] = *(const bf16x8*)(Q + (size_t)(b * S_ + q0 + mt * 16 + r16) * DOUT +
                                    h * HD + kk * 32 + quad * 8);

  bf16x4 ones4;
#pragma unroll
  for (int i = 0; i < 4; ++i) ones4[i] = (short)0x3F80;

  f32x4 zero = {0.f, 0.f, 0.f, 0.f};
  f32x4 o[2][4];  // [mt][dt]; C layout: row=q=quad*4+r, col=d=dt*16+r16
  f32x4 l[2];
#pragma unroll
  for (int mt = 0; mt < 2; ++mt) {
    l[mt] = zero;
#pragma unroll
    for (int dt = 0; dt < 4; ++dt) o[mt][dt] = zero;
  }

  // Stage one PAIR of KV tiles (both parities) into dbuf d; each wave stages
  // its 8-row segment of all 4 tile-slots (4 gld_lds/wave). Odd tile clamped
  // (redundant load, unused) when 2s+1 >= ntiles.
  auto stage_pair = [&](int d, int s) {
    const int t0 = 2 * s;
    const int t1 = (2 * s + 1 < ntiles) ? 2 * s + 1 : ntiles - 1;
    unsigned short* k0 = smem + (d * 2 + 0) * 4096;
    unsigned short* k1 = smem + (d * 2 + 1) * 4096;
    unsigned short* v0 = smem + 16384 + (d * 2 + 0) * 4096;
    unsigned short* v1 = smem + 16384 + (d * 2 + 1) * 4096;
    gld_lds16(Kh + (size_t)(t0 * 64 + wave * 8 + srow) * HD + schunk * 8, k0 + wave * 512);
    gld_lds16(Kh + (size_t)(t1 * 64 + wave * 8 + srow) * HD + schunk * 8, k1 + wave * 512);
    gld_lds16(VTh + (size_t)(wave * 8 + srow) * S_ + t0 * 64 + schunk * 8, v0 + wave * 512);
    gld_lds16(VTh + (size_t)(wave * 8 + srow) * S_ + t1 * 64 + schunk * 8, v1 + wave * 512);
  };

  stage_pair(0, 0);
  __syncthreads();

  for (int s = 0; s < nrounds; ++s) {
    const int d = s & 1;
    if (s + 1 < nrounds) stage_pair(d ^ 1, s + 1);

    const int t = 2 * s + p;
    if (t < ntiles) {
      const unsigned short* Kc = smem + (d * 2 + p) * 4096;
      const unsigned short* Vc = smem + 16384 + (d * 2 + p) * 4096;
      const bool last = (t == ntiles - 1);

      // K fragments: A-operand of S^T MFMA (m=key=r16 within tile nt)
      bf16x8 bk[4][2];
#pragma unroll
      for (int nt = 0; nt < 4; ++nt)
#pragma unroll
        for (int kk = 0; kk < 2; ++kk) {
          const int seg = nt * 2 + (r16 >> 3), r = r16 & 7;
          const int slot = (kk * 4 + quad) ^ r;
          bk[nt][kk] = *(const bf16x8*)&Kc[seg * 512 + r * 64 + slot * 8];
        }

#pragma unroll
      for (int mt = 0; mt < 2; ++mt) {
        // S^T = K.Q^T
        f32x4 st[4];
#pragma unroll
        for (int nt = 0; nt < 4; ++nt) st[nt] = zero;
#pragma unroll
        for (int kk = 0; kk < 2; ++kk)
#pragma unroll
          for (int nt = 0; nt < 4; ++nt)
            st[nt] = __builtin_amdgcn_mfma_f32_16x16x32_bf16(bk[nt][kk], aq[mt][kk], st[nt], 0, 0, 0);

        // mask + exp2 -> P A-fragments (K=16 layout), truncating bf16 pack
        bf16x4 pf[4];
#pragma unroll
        for (int nt = 0; nt < 4; ++nt) {
#pragma unroll
          for (int r = 0; r < 4; ++r) {
            float s2 = st[nt][r];
            if (last) {
              const int key = t * 64 + nt * 16 + quad * 4 + r;
              const int row = q0 + mt * 16 + r16;
              if (key > row) s2 = -1e38f;
            }
            const float pp = __builtin_amdgcn_exp2f(s2);
            pf[nt][r] = (short)(__float_as_uint(pp) >> 16);
          }
        }
        // row-sums via ones-MFMA, then PV with just-in-time V fragments
#pragma unroll
        for (int nt = 0; nt < 4; ++nt) l[mt] = mfma16(pf[nt], ones4, l[mt]);
#pragma unroll
        for (int dt = 0; dt < 4; ++dt) {
          const int seg = dt * 2 + (r16 >> 3), r = r16 & 7;
#pragma unroll
          for (int nt = 0; nt < 4; ++nt) {
            const int slot = (nt * 2 + (quad >> 1)) ^ r;
            bf16x4 bv = *(const bf16x4*)&Vc[seg * 512 + r * 64 + slot * 8 + (quad & 1) * 4];
            o[mt][dt] = mfma16(pf[nt], bv, o[mt][dt]);
          }
        }
      }
    }

    __syncthreads();  // prefetch landed + all reads of dbuf d done
  }

  // --- additive merge across the parity pair (m=0 softmax => no rescale).
  // LDS is free (loop's final __syncthreads drained everything).
  float* sm = (float*)smem;
  float* basep = sm + ((size_t)(hw * 64 + lane)) * 41;
  if (p == 1) {
#pragma unroll
    for (int mt = 0; mt < 2; ++mt)
#pragma unroll
      for (int dt = 0; dt < 4; ++dt)
#pragma unroll
        for (int r = 0; r < 4; ++r)
          basep[(mt * 4 + dt) * 4 + r] = o[mt][dt][r];
#pragma unroll
    for (int mt = 0; mt < 2; ++mt)
#pragma unroll
      for (int r = 0; r < 4; ++r)
        basep[32 + mt * 4 + r] = l[mt][r];
  }
  __syncthreads();
  if (p == 0) {
#pragma unroll
    for (int mt = 0; mt < 2; ++mt) {
#pragma unroll
      for (int dt = 0; dt < 4; ++dt)
#pragma unroll
        for (int r = 0; r < 4; ++r)
          o[mt][dt][r] += basep[(mt * 4 + dt) * 4 + r];
#pragma unroll
      for (int r = 0; r < 4; ++r)
        l[mt][r] += basep[32 + mt * 4 + r];
    }
#pragma unroll
    for (int mt = 0; mt < 2; ++mt) {
      f32x4 rl;
#pragma unroll
      for (int r = 0; r < 4; ++r) rl[r] = __builtin_amdgcn_rcpf(l[mt][r]);
#pragma unroll
      for (int dt = 0; dt < 4; ++dt)
#pragma unroll
        for (int r = 0; r < 4; ++r) {
          const int qq = q0 + mt * 16 + quad * 4 + r;
          ctx[(size_t)(b * S_ + qq) * DOUT + h * HD + dt * 16 + r16] =
              f2bf(o[mt][dt][r] * rl[r]);
        }
    }
  }
}

extern "C" void kernel_launch(void* const* d_in, const int* in_sizes, int n_in,
                              void* d_out, int out_size, void* d_ws, size_t ws_size,
                              hipStream_t stream) {
  const float* x  = (const float*)d_in[0];
  const float* Wq = (const float*)d_in[1];
  const float* Wk = (const float*)d_in[2];
  const float* Wv = (const float*)d_in[3];
  const float* Wo = (const float*)d_in[4];

  float* out  = (float*)d_out;
  float* keys = out + (size_t)B_ * S_ * DOUT;
  float* vals = keys + (size_t)B_ * NKV * S_ * HD;

  unsigned short* xbf  = (unsigned short*)d_ws;
  unsigned short* wqkv = xbf  + (size_t)B_ * S_ * DIN;
  unsigned short* wobf = wqkv + (size_t)NQKV * DIN;
  unsigned short* qbf  = wobf + (size_t)DIN * DOUT;
  unsigned short* kbf  = qbf  + (size_t)B_ * S_ * DOUT;
  unsigned short* vtbf = kbf  + (size_t)B_ * NKV * S_ * HD;
  unsigned short* ctx  = vtbf + (size_t)B_ * NKV * S_ * HD;

  cvt_all<<<dim3(4718592 / 256), dim3(256), 0, stream>>>(x, Wq, Wk, Wv, Wo,
                                                         xbf, wqkv, wobf);

  // QKV: M=4096, N=3072, 256x256 tiles -> 16x12 = 192 blocks (one round).
  gemm8p<0, 256, 12><<<dim3(192), dim3(512), 0, stream>>>(
      xbf, wqkv, DIN, qbf, kbf, vtbf, keys, vals, nullptr);

  // attn: 64 q-tiles (heavy-first) x NKV x B, 8 waves (4 heads x 2 parity).
  attn_kernel<<<dim3(64, NKV, B_), dim3(512), 0, stream>>>(qbf, kbf, vtbf, ctx);

  // Wo: M=4096, N=2048, 256x128 tiles -> 16x16 = 256 blocks (100% coverage).
  gemm8p<1, 128, 16><<<dim3(256), dim3(512), 0, stream>>>(
      ctx, wobf, DOUT, nullptr, nullptr, nullptr, nullptr, nullptr, out);
}

// Round 11
// 294.321 us; speedup vs baseline: 1.1104x; 1.1104x over previous
//
#include <hip/hip_runtime.h>

// GQA fused pipeline, bf16 MFMA, gfx950.  [SESSION-BEST: R7 revert]
// cvt(fp32->bf16) -> fused QKV GEMM (2-K-tile/8-phase, waits at Ph3/Ph7,
// publish-barrier-correct pipelined asm ds_reads, T2 swizzle + T5 setprio)
// -> flash attention (R1 structure: heavy+light q-tile pairing, dbuf
// prefetch, plain LDS reads + __syncthreads) -> Wo GEMM (256x128 tile).
//
// PUBLISH RULE (R6 lesson): vmcnt is PER-WAVE; half-tiles are staged
// cooperatively. A ds_read of a staged region is legal only after a barrier
// that follows every wave's counted vmcnt-wait landing that region.
// OCCUPANCY RULE (R8 lesson): launch_bounds 2nd arg caps VGPR (waves/SIMD =
// 8 -> 64 VGPR); asm-read pipelines at that cap spill ~90 regs/thread.

#define B_   2
#define S_   2048
#define DIN  2048
#define NH   32
#define NKV  8
#define HD   64
#define DOUT 2048
#define NQKV 3072

#define QSCALE 0.18033688f  // 0.125 * log2(e), folded into Q

typedef short bf16x8 __attribute__((ext_vector_type(8)));
typedef short bf16x4 __attribute__((ext_vector_type(4)));
typedef float f32x4  __attribute__((ext_vector_type(4)));

__device__ __forceinline__ unsigned short f2bf(float f) {
  unsigned int u = __float_as_uint(f);
  u += 0x7fff + ((u >> 16) & 1);  // RNE
  return (unsigned short)(u >> 16);
}

__device__ __forceinline__ f32x4 mfma16(bf16x4 a, bf16x4 b, f32x4 c) {
#if __has_builtin(__builtin_amdgcn_mfma_f32_16x16x16bf16_1k)
  return __builtin_amdgcn_mfma_f32_16x16x16bf16_1k(a, b, c, 0, 0, 0);
#else
  asm volatile("v_mfma_f32_16x16x16_bf16 %0, %1, %2, %0" : "+v"(c) : "v"(a), "v"(b));
  return c;
#endif
}

__device__ __forceinline__ void gld_lds16(const void* gptr, void* lptr) {
  __builtin_amdgcn_global_load_lds(
      (const __attribute__((address_space(1))) unsigned int*)gptr,
      (__attribute__((address_space(3))) unsigned int*)lptr,
      16, 0, 0);
}

// Inline-asm LDS read: invisible to the backend's aliasing analysis (no
// compiler-inserted vmcnt(0) against outstanding global_load_lds). Ordering
// is the ledger's job. Consumption needs lgkmcnt(0)+sched_barrier(0).
__device__ __forceinline__ bf16x8 ds_read128(const unsigned short* p) {
  bf16x8 r;
  asm volatile("ds_read_b128 %0, %1"
               : "=v"(r)
               : "v"((const __attribute__((address_space(3))) unsigned short*)p));
  return r;
}

#define BAR() __builtin_amdgcn_s_barrier()
#define SB()  __builtin_amdgcn_sched_barrier(0)
#define VMCNT(n) asm volatile("s_waitcnt vmcnt(" #n ")")
#define LGKM0()                                   \
  do {                                            \
    asm volatile("s_waitcnt lgkmcnt(0)");         \
    __builtin_amdgcn_sched_barrier(0);            \
  } while (0)

// single conversion kernel for all 5 tensors (boundaries multiples of 256).
__global__ __launch_bounds__(256) void cvt_all(
    const float* __restrict__ x,  const float* __restrict__ Wq,
    const float* __restrict__ Wk, const float* __restrict__ Wv,
    const float* __restrict__ Wo,
    unsigned short* __restrict__ xbf, unsigned short* __restrict__ wqkv,
    unsigned short* __restrict__ wobf) {
  int i = blockIdx.x * blockDim.x + threadIdx.x;
  const float* src; unsigned short* dst; int off;
  if (i < 2097152)      { src = x;  dst = xbf;                  off = i; }
  else if (i < 3145728) { src = Wq; dst = wqkv;                 off = i - 2097152; }
  else if (i < 3407872) { src = Wk; dst = wqkv + 2048 * 2048;   off = i - 3145728; }
  else if (i < 3670016) { src = Wv; dst = wqkv + 2560 * 2048;   off = i - 3407872; }
  else                  { src = Wo; dst = wobf;                 off = i - 3670016; }
  float4 f = ((const float4*)src)[off];
  ushort4 o;
  o.x = f2bf(f.x); o.y = f2bf(f.y); o.z = f2bf(f.z); o.w = f2bf(f.w);
  ((ushort4*)dst)[off] = o;
}

// C = A @ B^T, 256x(BN) tile, BK=64, 8 waves (2M x 4N), 512 threads.
// 2 K-tiles/iter, 8 phases, one half-tile stage per phase.
// Stage ledger (iter i, e=2i buf0, o=2i+1 buf1):
//   S1=A1(o)b1  S2=A0(e+2)b0 S3=B0(e+2)b0 S4=B1(e+2)b0
//   S5=A1(e+2)b0 S6=A0(o+2)b1 S7=B0(o+2)b1 S8=B1(o+2)b1
// Counted waits at END of Ph3 (W1) and Ph7 (W2): vmcnt(4) BN=256 /
// vmcnt(3) BN=128. W1 completes {prevS6,prevS7,prevS8,S1} = tile o;
// W2 completes {S2..S5} = tile e+2. Publish barriers = Ph3/Ph7 ending BARs.
// Reads: Ph4/Ph8 issue next tile's A0/B0 (after publish BAR, before MFMA ->
// drain overlaps MFMA); Ph1/Ph5 hoist B1, Ph2/Ph6 hoist A1 (data published
// >=1 barrier earlier). Every read retires at the NEXT phase's lgkmcnt(0).
// All 8 region WARs: overwrite issues >=1 barrier after last read retired.
#define MMA_PHASE(MH, NHH, AF, BF)                                              \
  do {                                                                          \
    __builtin_amdgcn_s_setprio(1);                                              \
    _Pragma("unroll")                                                           \
    for (int kk = 0; kk < 2; ++kk)                                              \
      _Pragma("unroll")                                                         \
      for (int mr = 0; mr < 4; ++mr)                                            \
        _Pragma("unroll")                                                       \
        for (int nr = 0; nr < NR; ++nr)                                         \
          acc[(MH) * 4 + mr][(NHH) * NR + nr] =                                 \
              __builtin_amdgcn_mfma_f32_16x16x32_bf16(                          \
                  AF[mr][kk], BF[nr][kk], acc[(MH) * 4 + mr][(NHH) * NR + nr],  \
                  0, 0, 0);                                                     \
    __builtin_amdgcn_s_setprio(0);                                              \
  } while (0)

#define WAITW()                                   \
  do {                                            \
    if constexpr (BN == 256) VMCNT(4);            \
    else                     VMCNT(3);            \
  } while (0)

template <int MODE, int BN, int NTN>
__global__ __launch_bounds__(512, 2) void gemm8p(
    const unsigned short* __restrict__ A,
    const unsigned short* __restrict__ Bm,
    int K,
    unsigned short* __restrict__ qbf,
    unsigned short* __restrict__ kbf,
    unsigned short* __restrict__ vtbf,
    float* __restrict__ kout,
    float* __restrict__ vout,
    float* __restrict__ cout) {
  constexpr int NR = BN / 128;        // B fragments per quadrant (2 or 1)
  constexpr int BHROW = BN / 2;       // rows per B half-tile
  __shared__ unsigned short As[2][256 * 64];
  __shared__ unsigned short Bs[2][BN * 64];

  const int tid  = threadIdx.x;
  const int lane = tid & 63;
  const int wave = tid >> 6;  // 0..7
  const int wm   = wave >> 2; // 0..1
  const int wn   = wave & 3;  // 0..3
  const int quad = lane >> 4;
  const int r16  = lane & 15;

  const int NT = K / 64;

  // XCD-aware chunked swizzle on linear block id (gridDim.x % 8 == 0).
  const int nwg = gridDim.x;
  const int id  = blockIdx.x;
  const int sid = (id & 7) * (nwg >> 3) + (id >> 3);
  const int by  = sid / NTN;
  const int bx  = sid % NTN;
  const int aRowBase = by * 256;
  const int bColBase = bx * BN;

  f32x4 zero = {0.f, 0.f, 0.f, 0.f};
  f32x4 acc[8][2 * NR];
#pragma unroll
  for (int i = 0; i < 8; ++i)
#pragma unroll
    for (int j = 0; j < 2 * NR; ++j) acc[i][j] = zero;

  // --- staging: one half-tile per call; LDS dest linear; global source
  // pre-swizzled so LDS holds chunk slot ^ (row&7) (T2 both-sides, rule #21).
  auto stageA = [&](int dbuf, int h, int t) {
    const int tt = t < NT ? t : NT - 1;
    const int k0 = tt * 64;
#pragma unroll
    for (int i = 0; i < 2; ++i) {
      const int chunk = (i * 8 + wave) * 64 + lane;  // 0..1023
      const int row = chunk >> 3;                    // 0..127
      const int slot = chunk & 7;
      const int gc = (slot ^ (row & 7)) * 8;
      gld_lds16(A + (size_t)(aRowBase + h * 128 + row) * K + k0 + gc,
                &As[dbuf][h * 8192 + (i * 8 + wave) * 512]);
    }
  };
  auto stageB = [&](int dbuf, int h, int t) {
    const int tt = t < NT ? t : NT - 1;
    const int k0 = tt * 64;
    if constexpr (BN == 256) {
#pragma unroll
      for (int i = 0; i < 2; ++i) {
        const int chunk = (i * 8 + wave) * 64 + lane;
        const int row = chunk >> 3;
        const int slot = chunk & 7;
        const int gc = (slot ^ (row & 7)) * 8;
        gld_lds16(Bm + (size_t)(bColBase + h * 128 + row) * K + k0 + gc,
                  &Bs[dbuf][h * 8192 + (i * 8 + wave) * 512]);
      }
    } else {
      const int chunk = wave * 64 + lane;  // 0..511
      const int row = chunk >> 3;          // 0..63
      const int slot = chunk & 7;
      const int gc = (slot ^ (row & 7)) * 8;
      gld_lds16(Bm + (size_t)(bColBase + h * 64 + row) * K + k0 + gc,
                &Bs[dbuf][h * 4096 + wave * 512]);
    }
  };

  bf16x8 afA[4][2];     // A-half0 fragments
  bf16x8 afB[4][2];     // A-half1 fragments
  bf16x8 b0[NR][2];     // B-half0 fragments
  bf16x8 b1[NR][2];     // B-half1 fragments

  auto readA = [&](int sbuf, int mh, bf16x8 (&dst)[4][2]) {
#pragma unroll
    for (int mr = 0; mr < 4; ++mr)
#pragma unroll
      for (int kk = 0; kk < 2; ++kk) {
        const int row = mh * 128 + wm * 64 + mr * 16 + r16;
        const int slot = (kk * 4 + quad) ^ (r16 & 7);
        dst[mr][kk] = ds_read128(&As[sbuf][row * 64 + slot * 8]);
      }
  };
  auto readB = [&](int sbuf, int nh, bf16x8 (&dst)[NR][2]) {
#pragma unroll
    for (int nr = 0; nr < NR; ++nr)
#pragma unroll
      for (int kk = 0; kk < 2; ++kk) {
        const int row = nh * BHROW + wn * (BN / 8) + nr * 16 + r16;
        const int slot = (kk * 4 + quad) ^ (r16 & 7);
        dst[nr][kk] = ds_read128(&Bs[sbuf][row * 64 + slot * 8]);
      }
  };

  // --- prologue: mirrors steady state at Ph1 entry.
  stageA(0, 0, 0);   // A0(0)
  stageB(0, 0, 0);   // B0(0)
  stageB(0, 1, 0);   // B1(0)
  stageA(0, 1, 0);   // A1(0)
  stageA(1, 0, 1);   // A0(1)
  stageB(1, 0, 1);   // B0(1)
  WAITW();           // lands tile0; leaves {A0(1),B0(1)}
  BAR();             // PUBLISH tile0
  stageB(1, 1, 1);   // B1(1)
  readA(0, 0, afA);
  readB(0, 0, b0);
  SB();

  const int NIT = NT / 2;
  for (int i = 0; i < NIT; ++i) {
    const int e2 = 2 * i + 2, o2 = 2 * i + 3;

    // Ph1 (e,q00): consume afA,b0; hoist B1(e)->b1 (published prev Ph7).
    stageA(1, 1, 2 * i + 1);              // S1
    BAR();
    LGKM0();
    readB(0, 1, b1); SB();
    MMA_PHASE(0, 0, afA, b0);
    BAR();

    // Ph2 (e,q01): consume afA,b1; hoist A1(e)->afB (published prev Ph7).
    stageA(0, 0, e2);                     // S2
    BAR();
    LGKM0();
    readA(0, 1, afB); SB();
    MMA_PHASE(0, 1, afA, b1);
    BAR();

    // Ph3 (e,q10): consume afB,b0; counted wait W1 lands tile o.
    stageB(0, 0, e2);                     // S3
    BAR();
    LGKM0();
    MMA_PHASE(1, 0, afB, b0);
    WAITW();                              // W1: {prevS6,prevS7,prevS8,S1}
    BAR();                                // PUBLISH tile o

    // Ph4 (e,q11): register-only MFMA; read A0(o),B0(o) overlapping MFMA.
    stageB(0, 1, e2);                     // S4
    BAR();
    readA(1, 0, afA);
    readB(1, 0, b0); SB();
    MMA_PHASE(1, 1, afB, b1);
    BAR();

    // Ph5 (o,q00): consume afA,b0; hoist B1(o)->b1 (published Ph3).
    stageA(0, 1, e2);                     // S5
    BAR();
    LGKM0();
    readB(1, 1, b1); SB();
    MMA_PHASE(0, 0, afA, b0);
    BAR();

    // Ph6 (o,q01): consume afA,b1; hoist A1(o)->afB (published Ph3).
    stageA(1, 0, o2);                     // S6
    BAR();
    LGKM0();
    readA(1, 1, afB); SB();
    MMA_PHASE(0, 1, afA, b1);
    BAR();

    // Ph7 (o,q10): consume afB,b0; counted wait W2 lands tile e+2.
    stageB(1, 0, o2);                     // S7
    BAR();
    LGKM0();
    MMA_PHASE(1, 0, afB, b0);
    WAITW();                              // W2: {S2,S3,S4,S5}
    BAR();                                // PUBLISH tile e+2

    // Ph8 (o,q11): register-only MFMA; read A0(e'),B0(e') overlapping MFMA.
    stageB(1, 1, o2);                     // S8
    BAR();
    readA(0, 0, afA);
    readB(0, 0, b0); SB();
    MMA_PHASE(1, 1, afB, b1);
    BAR();
  }
  asm volatile("s_waitcnt vmcnt(0) lgkmcnt(0)");  // drain before epilogue

  // --- epilogue: C write.
#pragma unroll
  for (int mi = 0; mi < 8; ++mi) {
    const int mh = mi >> 2, mr = mi & 3;
#pragma unroll
    for (int ni = 0; ni < 2 * NR; ++ni) {
      const int nh = ni / NR, nr = ni % NR;
      const int rowb = aRowBase + mh * 128 + wm * 64 + mr * 16 + quad * 4;
      const int col  = bColBase +
                       (BN == 256 ? nh * 128 + wn * 32 + nr * 16
                                  : nh * 64 + wn * 16) + r16;
#pragma unroll
      for (int reg = 0; reg < 4; ++reg) {
        const float v = acc[mi][ni][reg];
        const int m = rowb + reg;
        if (MODE == 1) {
          cout[(size_t)m * DOUT + col] = v;
        } else {
          if (col < 2048) {
            qbf[(size_t)m * DOUT + col] = f2bf(v * QSCALE);
          } else if (col < 2560) {
            const int gg = (col - 2048) >> 6, d = col & 63;
            const int b = m >> 11, s = m & 2047;
            const size_t idx = ((size_t)(b * NKV + gg) * S_ + s) * HD + d;
            kbf[idx]  = f2bf(v);
            kout[idx] = v;
          } else {
            const int gg = (col - 2560) >> 6, d = col & 63;
            const int b = m >> 11, s = m & 2047;
            vtbf[((size_t)(b * NKV + gg) * HD + d) * S_ + s]  = f2bf(v);
            vout[((size_t)(b * NKV + gg) * S_ + s) * HD + d] = v;
          }
        }
      }
    }
  }
}

// Flash attention, causal, m=0 softmax, in-register P (S^T operand-swap).
// 8 waves: group 0 (waves 0-3) = heavy tile (63-pairI), group 1 = light tile
// (pairI); wave = one head. K/V double-buffered via global_load_lds with
// prefetch-before-compute. Best attn structure measured this session
// (~85 us; depth-2 counted-vmcnt = 90.4, parity-split = 101.0).
__global__ __launch_bounds__(512, 4) void attn_kernel(
    const unsigned short* __restrict__ Q,   // [B*S][DOUT] bf16 (scaled)
    const unsigned short* __restrict__ Kb,  // [B*NKV][S][HD] bf16
    const unsigned short* __restrict__ VT,  // [B*NKV][HD][S] bf16
    unsigned short* __restrict__ ctx) {     // [B*S][DOUT] bf16
  __shared__ unsigned short Kbuf[2][4096];  // 64 keys x 64 d, XOR-swizzled
  __shared__ unsigned short Vbuf[2][4096];  // 64 d x 64 keys, XOR-swizzled

  const int tid  = threadIdx.x;
  const int lane = tid & 63;
  const int wave = tid >> 6;   // 0..7
  const int grp  = wave >> 2;  // 0 = heavy tile, 1 = light tile
  const int hw   = wave & 3;
  const int quad = lane >> 4;
  const int r16  = lane & 15;
  const int g    = blockIdx.y;
  const int b    = blockIdx.z;
  const int h    = g * 4 + hw;
  const int pairI = blockIdx.x;  // 0..31, heavy-first
  const int q0     = grp ? pairI * 32 : (63 - pairI) * 32;
  const int nT_own = grp ? pairI / 2 + 1 : (63 - pairI) / 2 + 1;
  const int nTa    = (63 - pairI) / 2 + 1;  // block loop bound

  const unsigned short* Kh  = Kb + (size_t)(b * NKV + g) * S_ * HD;
  const unsigned short* VTh = VT + (size_t)(b * NKV + g) * HD * S_;

  const int srow   = lane >> 3;
  const int schunk = (lane & 7) ^ srow;

  // Q fragments (B-operand of S^T MFMA; same layout as A-operand)
  bf16x8 aq[2][2];
#pragma unroll
  for (int mt = 0; mt < 2; ++mt)
#pragma unroll
    for (int kk = 0; kk < 2; ++kk)
      aq[mt][kk] = *(const bf16x8*)(Q + (size_t)(b * S_ + q0 + mt * 16 + r16) * DOUT +
                                    h * HD + kk * 32 + quad * 8);

  bf16x4 ones4;
#pragma unroll
  for (int i = 0; i < 4; ++i) ones4[i] = (short)0x3F80;

  f32x4 zero = {0.f, 0.f, 0.f, 0.f};
  f32x4 o[2][4];  // [mt][dt]; C layout: row=q=quad*4+r, col=d=dt*16+r16
  f32x4 l[2];
#pragma unroll
  for (int mt = 0; mt < 2; ++mt) {
    l[mt] = zero;
#pragma unroll
    for (int dt = 0; dt < 4; ++dt) o[mt][dt] = zero;
  }

  // each wave stages one 8-row segment of K and of V^T (wave-uniform base)
  auto stage = [&](int buf, int kt) {
    const int kbase = kt * 64;
    gld_lds16(Kh + (size_t)(kbase + wave * 8 + srow) * HD + schunk * 8,
              &Kbuf[buf][wave * 512]);
    gld_lds16(VTh + (size_t)(wave * 8 + srow) * S_ + kbase + schunk * 8,
              &Vbuf[buf][wave * 512]);
  };

  stage(0, 0);
  __syncthreads();

  for (int kt = 0; kt < nTa; ++kt) {
    const int buf = kt & 1;
    if (kt + 1 < nTa) stage(buf ^ 1, kt + 1);

    if (kt < nT_own) {
      // K fragments: A-operand of S^T MFMA (m=key=r16 within tile nt)
      bf16x8 bk[4][2];
#pragma unroll
      for (int nt = 0; nt < 4; ++nt)
#pragma unroll
        for (int kk = 0; kk < 2; ++kk) {
          const int seg = nt * 2 + (r16 >> 3), r = r16 & 7;
          const int slot = (kk * 4 + quad) ^ r;
          bk[nt][kk] = *(const bf16x8*)&Kbuf[buf][seg * 512 + r * 64 + slot * 8];
        }

      const bool last = (kt == nT_own - 1);
#pragma unroll
      for (int mt = 0; mt < 2; ++mt) {
        // S^T = K.Q^T
        f32x4 st[4];
#pragma unroll
        for (int nt = 0; nt < 4; ++nt) st[nt] = zero;
#pragma unroll
        for (int kk = 0; kk < 2; ++kk)
#pragma unroll
          for (int nt = 0; nt < 4; ++nt)
            st[nt] = __builtin_amdgcn_mfma_f32_16x16x32_bf16(bk[nt][kk], aq[mt][kk], st[nt], 0, 0, 0);

        // mask + exp2 -> P A-fragments (K=16 layout), truncating bf16 pack
        bf16x4 pf[4];
#pragma unroll
        for (int nt = 0; nt < 4; ++nt) {
#pragma unroll
          for (int r = 0; r < 4; ++r) {
            float s = st[nt][r];
            if (last) {
              const int key = kt * 64 + nt * 16 + quad * 4 + r;
              const int row = q0 + mt * 16 + r16;
              if (key > row) s = -1e38f;
            }
            const float p = __builtin_amdgcn_exp2f(s);
            pf[nt][r] = (short)(__float_as_uint(p) >> 16);
          }
        }
        // row-sums via ones-MFMA, then PV with just-in-time V fragments
#pragma unroll
        for (int nt = 0; nt < 4; ++nt) l[mt] = mfma16(pf[nt], ones4, l[mt]);
#pragma unroll
        for (int dt = 0; dt < 4; ++dt) {
          const int seg = dt * 2 + (r16 >> 3), r = r16 & 7;
#pragma unroll
          for (int nt = 0; nt < 4; ++nt) {
            const int slot = (nt * 2 + (quad >> 1)) ^ r;
            bf16x4 bv = *(const bf16x4*)&Vbuf[buf][seg * 512 + r * 64 + slot * 8 + (quad & 1) * 4];
            o[mt][dt] = mfma16(pf[nt], bv, o[mt][dt]);
          }
        }
      }
    }

    __syncthreads();  // prefetch aged a full compute phase; swap buffers
  }

#pragma unroll
  for (int mt = 0; mt < 2; ++mt) {
    f32x4 rl;
#pragma unroll
    for (int r = 0; r < 4; ++r) rl[r] = __builtin_amdgcn_rcpf(l[mt][r]);
#pragma unroll
    for (int dt = 0; dt < 4; ++dt)
#pragma unroll
      for (int r = 0; r < 4; ++r) {
        const int qq = q0 + mt * 16 + quad * 4 + r;
        ctx[(size_t)(b * S_ + qq) * DOUT + h * HD + dt * 16 + r16] =
            f2bf(o[mt][dt][r] * rl[r]);
      }
  }
}

extern "C" void kernel_launch(void* const* d_in, const int* in_sizes, int n_in,
                              void* d_out, int out_size, void* d_ws, size_t ws_size,
                              hipStream_t stream) {
  const float* x  = (const float*)d_in[0];
  const float* Wq = (const float*)d_in[1];
  const float* Wk = (const float*)d_in[2];
  const float* Wv = (const float*)d_in[3];
  const float* Wo = (const float*)d_in[4];

  float* out  = (float*)d_out;
  float* keys = out + (size_t)B_ * S_ * DOUT;
  float* vals = keys + (size_t)B_ * NKV * S_ * HD;

  unsigned short* xbf  = (unsigned short*)d_ws;
  unsigned short* wqkv = xbf  + (size_t)B_ * S_ * DIN;
  unsigned short* wobf = wqkv + (size_t)NQKV * DIN;
  unsigned short* qbf  = wobf + (size_t)DIN * DOUT;
  unsigned short* kbf  = qbf  + (size_t)B_ * S_ * DOUT;
  unsigned short* vtbf = kbf  + (size_t)B_ * NKV * S_ * HD;
  unsigned short* ctx  = vtbf + (size_t)B_ * NKV * S_ * HD;

  cvt_all<<<dim3(4718592 / 256), dim3(256), 0, stream>>>(x, Wq, Wk, Wv, Wo,
                                                         xbf, wqkv, wobf);

  // QKV: M=4096, N=3072, 256x256 tiles -> 16x12 = 192 blocks (one round).
  gemm8p<0, 256, 12><<<dim3(192), dim3(512), 0, stream>>>(
      xbf, wqkv, DIN, qbf, kbf, vtbf, keys, vals, nullptr);

  attn_kernel<<<dim3(32, NKV, B_), dim3(512), 0, stream>>>(qbf, kbf, vtbf, ctx);

  // Wo: M=4096, N=2048, 256x128 tiles -> 16x16 = 256 blocks (100% coverage).
  gemm8p<1, 128, 16><<<dim3(256), dim3(512), 0, stream>>>(
      ctx, wobf, DOUT, nullptr, nullptr, nullptr, nullptr, nullptr, out);
}